// Round 5
// baseline (316.437 us; speedup 1.0000x reference)
//
#include <hip/hip_runtime.h>
#include <hip/hip_bf16.h>

// VSSBlock (VMamba SS2D) forward for B=8,H=32,W=32,C=192 on gfx950.
// Round 5: barrier-free LDS-free MFMA GEMMs. Weights held in registers per
// 192-deep K-chunk (16-col strip per wave); A fragments streamed directly
// from global (L2-resident). No __syncthreads in any GEMM.

typedef __hip_bfloat16 bf16;
#define DEV __device__ __forceinline__

typedef __attribute__((ext_vector_type(8))) short short8;
typedef __attribute__((ext_vector_type(4))) float floatx4;

constexpr int Bb   = 8;
constexpr int Hh   = 32;
constexpr int Ww   = 32;
constexpr int Cc   = 192;
constexpr int DI   = 384;
constexpr int Ss   = 16;
constexpr int Rr   = 12;
constexpr int HID  = 768;
constexpr int Mm   = 8192;   // B*H*W
constexpr int XDP  = 48;     // padded x_dbl row stride (44 -> 48)
constexpr int NCH  = 64;     // scan chunks
constexpr int CLEN = 16;     // steps per chunk (NCH*CLEN == 1024)

DEV float sigmoid_f(float x) { return 1.0f / (1.0f + __expf(-x)); }
DEV float silu_f(float x) { return x * sigmoid_f(x); }
DEV float gelu_f(float x) {
    float x3 = x * x * x;
    float t  = tanhf(0.7978845608028654f * (x + 0.044715f * x3));
    return 0.5f * x * (1.0f + t);
}

DEV void st16(float* __restrict__ p, const float* v) {
    float4* q = (float4*)p;
    q[0] = make_float4(v[0],v[1],v[2],v[3]);
    q[1] = make_float4(v[4],v[5],v[6],v[7]);
    q[2] = make_float4(v[8],v[9],v[10],v[11]);
    q[3] = make_float4(v[12],v[13],v[14],v[15]);
}
DEV void ld16(const float* __restrict__ p, float* v) {
    const float4* q = (const float4*)p;
    float4 a = q[0], b = q[1], c = q[2], d = q[3];
    v[0]=a.x; v[1]=a.y; v[2]=a.z; v[3]=a.w;
    v[4]=b.x; v[5]=b.y; v[6]=b.z; v[7]=b.w;
    v[8]=c.x; v[9]=c.y; v[10]=c.z; v[11]=c.w;
    v[12]=d.x; v[13]=d.y; v[14]=d.z; v[15]=d.w;
}

// ---------------- dtype detect: ln1_g is ones(192) ----------------
__global__ void detect_kernel(const unsigned int* __restrict__ g, int* __restrict__ flag) {
    if (threadIdx.x == 0 && blockIdx.x == 0)
        flag[0] = (g[0] == 0x3F800000u) ? 1 : 0;
}

// ---------------- widen all weight tensors: fp32 + bf16 copies ----------------
struct Segs {
    const void* src[19];
    int off[20];
};
__global__ __launch_bounds__(256) void convert_w(Segs sg, float* __restrict__ dst,
                                                 bf16* __restrict__ dstb,
                                                 const int* __restrict__ flag) {
    int i = blockIdx.x * 256 + threadIdx.x;
    if (i >= sg.off[19]) return;
    int f = flag[0];
    int s = 0;
    while (i >= sg.off[s + 1]) s++;
    int j = i - sg.off[s];
    float v = f ? ((const float*)sg.src[s])[j] : (float)((const bf16*)sg.src[s])[j];
    dst[i] = v;
    dstb[i] = __float2bfloat16(v);
}

__global__ __launch_bounds__(256) void convert_x(const void* __restrict__ src,
                                                 float* __restrict__ dst, int n,
                                                 const int* __restrict__ flag) {
    int i = blockIdx.x * 256 + threadIdx.x;
    if (i >= n) return;
    dst[i] = flag[0] ? ((const float*)src)[i] : (float)((const bf16*)src)[i];
}

// ---------------- LayerNorm (one wave per row), bf16 output ----------------
template <int NC, bool MULSILU>
__global__ __launch_bounds__(256) void ln_kernel(
    const float* __restrict__ x, const float* __restrict__ g, const float* __restrict__ b,
    const float* __restrict__ zbuf, int zld, int zoff, bf16* __restrict__ out)
{
    constexpr int NPT = NC / 64;
    int wave = threadIdx.x >> 6, lane = threadIdx.x & 63;
    int row = blockIdx.x * 4 + wave;
    const float* xr = x + (size_t)row * NC;
    float v[NPT];
    float s = 0.f;
#pragma unroll
    for (int j = 0; j < NPT; j++) { v[j] = xr[lane + 64 * j]; s += v[j]; }
#pragma unroll
    for (int m = 1; m < 64; m <<= 1) s += __shfl_xor(s, m);
    float mu = s * (1.0f / NC);
    float s2 = 0.f;
#pragma unroll
    for (int j = 0; j < NPT; j++) { float d = v[j] - mu; s2 += d * d; }
#pragma unroll
    for (int m = 1; m < 64; m <<= 1) s2 += __shfl_xor(s2, m);
    float rs = rsqrtf(s2 * (1.0f / NC) + 1e-5f);
    bf16* orow = out + (size_t)row * NC;
#pragma unroll
    for (int j = 0; j < NPT; j++) {
        int c = lane + 64 * j;
        float val = (v[j] - mu) * rs * g[c] + b[c];
        if (MULSILU) {
            float z = zbuf[(size_t)row * zld + zoff + c];
            val *= silu_f(z);
        }
        orow[c] = __float2bfloat16(val);
    }
}

// ---------------- MFMA GEMM, barrier-free: C[M,N] = A[M,K](bf16) * B[N,K]^T ----------------
// Each wave owns a 16-wide n-strip (block covers 64 n). B-fragments for a
// 192-deep K-chunk live in registers; A-fragments load straight from global.
// Each thread owns output column n = n0 + wid*16 + l16 for MB rows.
// EPI: 0 = fp32 out; 1 = +fp32 residual, fp32 out; 2 = gelu(acc+bias) -> bf16;
//      3 = acc+bias+fp32 residual -> flag dtype.
template <int Kt, int KCH, int MB, int EPI>
__global__ __launch_bounds__(256) void mfma_gemm(
    const unsigned short* __restrict__ A, const unsigned short* __restrict__ Bw,
    int N, int lda, int ldb, int ldc,
    const float* __restrict__ bias, const float* __restrict__ res, int ldres,
    float* __restrict__ Cf, void* __restrict__ Co, const int* __restrict__ flagp)
{
    constexpr int MT = MB / 16;      // 16-row m-tiles per block
    constexpr int NK = KCH / 32;     // MFMA k-steps per K-chunk
    int tid = threadIdx.x;
    int wid = tid >> 6, lane = tid & 63;
    int quad = lane >> 4, l16 = lane & 15;
    int m0 = blockIdx.x * MB;
    int n0 = blockIdx.y * 64 + wid * 16;
    if (n0 >= N) return;             // idle wave (x_proj N=44)
    int n = n0 + l16;
    int br = (n < N) ? n : N - 1;    // clamped B row; garbage lanes never stored

    floatx4 acc[MT];
#pragma unroll
    for (int i = 0; i < MT; i++) acc[i] = (floatx4){0.f, 0.f, 0.f, 0.f};

    for (int kc = 0; kc < Kt; kc += KCH) {
        short8 bf[NK];
#pragma unroll
        for (int ks = 0; ks < NK; ks++)
            bf[ks] = *(const short8*)(Bw + (size_t)br * ldb + kc + ks * 32 + quad * 8);
#pragma unroll
        for (int mt = 0; mt < MT; mt++) {
#pragma unroll
            for (int ks = 0; ks < NK; ks++) {
                short8 af = *(const short8*)(A + (size_t)(m0 + mt * 16 + l16) * lda
                                             + kc + ks * 32 + quad * 8);
                acc[mt] = __builtin_amdgcn_mfma_f32_16x16x32_bf16(af, bf[ks], acc[mt], 0, 0, 0);
            }
        }
    }

    if (n >= N) return;
    int f = (EPI == 3) ? flagp[0] : 0;
    float bv = (EPI == 2 || EPI == 3) ? bias[n] : 0.f;
#pragma unroll
    for (int mt = 0; mt < MT; mt++) {
#pragma unroll
        for (int r = 0; r < 4; r++) {
            int m = m0 + mt * 16 + quad * 4 + r;
            float v = acc[mt][r];
            if (EPI == 1) {
                Cf[(size_t)m * ldc + n] = v + res[(size_t)m * ldres + n];
            } else if (EPI == 2) {
                ((bf16*)Co)[(size_t)m * ldc + n] = __float2bfloat16(gelu_f(v + bv));
            } else if (EPI == 3) {
                v += bv + res[(size_t)m * ldres + n];
                if (f) ((float*)Co)[(size_t)m * ldc + n] = v;
                else   ((bf16*)Co)[(size_t)m * ldc + n] = __float2bfloat16(v);
            } else {
                Cf[(size_t)m * ldc + n] = v;
            }
        }
    }
}

// ---------------- depthwise 3x3 conv + bias + SiLU (fp32 + bf16 out) ----------------
__global__ __launch_bounds__(384) void conv_silu_kernel(
    const float* __restrict__ xz, const float* __restrict__ cw,
    const float* __restrict__ cb, float* __restrict__ u, bf16* __restrict__ ub)
{
    int d = threadIdx.x;
    int blk = blockIdx.x;              // b*1024 + l
    int l = blk & 1023, b = blk >> 10;
    int h = l >> 5, w = l & 31;
    float wv[9];
#pragma unroll
    for (int t = 0; t < 9; t++) wv[t] = cw[d * 9 + t];
    float acc = cb[d];
#pragma unroll
    for (int ki = 0; ki < 3; ki++) {
        int hh = h + ki - 1;
        if (hh < 0 || hh >= Hh) continue;
#pragma unroll
        for (int kj = 0; kj < 3; kj++) {
            int ww = w + kj - 1;
            if (ww < 0 || ww >= Ww) continue;
            acc += xz[((size_t)(b << 10) + (hh << 5) + ww) * 768 + d] * wv[ki * 3 + kj];
        }
    }
    float s = silu_f(acc);
    u[(size_t)blk * DI + d] = s;
    ub[(size_t)blk * DI + d] = __float2bfloat16(s);
}

// ---------------- dt_proj + softplus -> delta ----------------
__global__ __launch_bounds__(256) void delta_kernel(
    const float* __restrict__ xdbl, const float* __restrict__ dtw,
    const float* __restrict__ dtb, float* __restrict__ dlt)
{
    int idx = blockIdx.x * 256 + threadIdx.x;   // m*384 + d
    int d = idx % DI, m = idx / DI;
    float acc = dtb[d];
    const float* xr = xdbl + (size_t)m * XDP;
#pragma unroll
    for (int r = 0; r < Rr; r++) acc += xr[r] * dtw[d * Rr + r];
    dlt[idx] = (acc > 20.f) ? acc : log1pf(__expf(acc));
}

// ---------------- scan pass A: per-chunk (prod dA, h_end), pipelined ----------------
__global__ __launch_bounds__(256) void scanA_kernel(
    const float* __restrict__ dlt, const float* __restrict__ u,
    const float* __restrict__ xdbl, const int* __restrict__ perm,
    const float* __restrict__ A_log,
    float* __restrict__ Hend, float* __restrict__ Pend)
{
    int wg = blockIdx.x * 4 + (threadIdx.x >> 6);
    int lane = threadIdx.x & 63;
    int dgrp = wg % 6; int rest = wg / 6;
    int chunk = rest % NCH; int b = rest / NCH;
    int d = dgrp * 64 + lane;

    int rowv = 0;
    if (lane < CLEN) rowv = (b << 10) + perm[chunk * CLEN + lane];

    float A2[16], h[16], P[16];
#pragma unroll
    for (int s = 0; s < 16; s++) {
        A2[s] = -__expf(A_log[d * 16 + s]) * 1.4426950408889634f;
        h[s] = 0.f; P[s] = 1.f;
    }

    int row = __shfl(rowv, 0);
    size_t base = (size_t)row * DI + d;
    float dl = dlt[base], uv = u[base];
    const float4* xb = (const float4*)(xdbl + (size_t)row * XDP);
    float4 B0 = xb[3], B1 = xb[4], B2 = xb[5], B3 = xb[6];

#pragma unroll 1
    for (int t = 0; t < CLEN; t++) {
        float dlc = dl;
        float dv  = dl * uv;
        float Bc[16] = {B0.x,B0.y,B0.z,B0.w, B1.x,B1.y,B1.z,B1.w,
                        B2.x,B2.y,B2.z,B2.w, B3.x,B3.y,B3.z,B3.w};
        if (t + 1 < CLEN) {   // prefetch next step while computing this one
            row = __shfl(rowv, t + 1);
            base = (size_t)row * DI + d;
            dl = dlt[base]; uv = u[base];
            xb = (const float4*)(xdbl + (size_t)row * XDP);
            B0 = xb[3]; B1 = xb[4]; B2 = xb[5]; B3 = xb[6];
        }
#pragma unroll
        for (int s = 0; s < 16; s++) {
            float dA = exp2f(dlc * A2[s]);
            h[s] = dA * h[s] + dv * Bc[s];
            P[s] *= dA;
        }
    }
    size_t o = ((size_t)((b * NCH + chunk) * DI + d)) * 16;
    st16(Hend + o, h);
    st16(Pend + o, P);
}

// ---------------- scan combine: in-place exclusive prefix over Hend ----------------
__global__ __launch_bounds__(256) void scan_combine_kernel(
    float* __restrict__ Hend, const float* __restrict__ Pend)
{
    int idx = blockIdx.x * 256 + threadIdx.x;   // b*(384*16) + d*16 + s
    int s = idx & 15; int dd = (idx >> 4) % DI; int b = (idx >> 4) / DI;
    float hv = 0.f;
    for (int c = 0; c < NCH; c++) {
        size_t o = ((size_t)((b * NCH + c) * DI + dd)) * 16 + s;
        float he = Hend[o], pe = Pend[o];
        Hend[o] = hv;                 // exclusive prefix (h_in for chunk c)
        hv = he + pe * hv;
    }
}

// ---------------- scan pass C: recompute with true h_in, emit y; pipelined ----------------
__global__ __launch_bounds__(256) void scanC_kernel(
    const float* __restrict__ dlt, const float* __restrict__ u,
    const float* __restrict__ xdbl, const int* __restrict__ perm,
    const float* __restrict__ A_log, const float* __restrict__ Dp,
    const float* __restrict__ Hin, float* __restrict__ y)
{
    int wg = blockIdx.x * 4 + (threadIdx.x >> 6);
    int lane = threadIdx.x & 63;
    int dgrp = wg % 6; int rest = wg / 6;
    int chunk = rest % NCH; int b = rest / NCH;
    int d = dgrp * 64 + lane;

    int rowv = 0;
    if (lane < CLEN) rowv = (b << 10) + perm[chunk * CLEN + lane];

    float A2[16], h[16];
#pragma unroll
    for (int s = 0; s < 16; s++)
        A2[s] = -__expf(A_log[d * 16 + s]) * 1.4426950408889634f;
    ld16(Hin + ((size_t)((b * NCH + chunk) * DI + d)) * 16, h);
    float dpv = Dp[d];

    int row = __shfl(rowv, 0);
    size_t base = (size_t)row * DI + d;
    float dl = dlt[base], uv = u[base];
    const float4* xb = (const float4*)(xdbl + (size_t)row * XDP);
    float4 B0 = xb[3], B1 = xb[4], B2 = xb[5], B3 = xb[6];
    float4 C0 = xb[7], C1 = xb[8], C2 = xb[9], C3 = xb[10];

#pragma unroll 1
    for (int t = 0; t < CLEN; t++) {
        int trow = row;
        float dlc = dl, uvc = uv;
        float dv  = dl * uv;
        float Bc[16] = {B0.x,B0.y,B0.z,B0.w, B1.x,B1.y,B1.z,B1.w,
                        B2.x,B2.y,B2.z,B2.w, B3.x,B3.y,B3.z,B3.w};
        float Cv[16] = {C0.x,C0.y,C0.z,C0.w, C1.x,C1.y,C1.z,C1.w,
                        C2.x,C2.y,C2.z,C2.w, C3.x,C3.y,C3.z,C3.w};
        if (t + 1 < CLEN) {   // prefetch next step while computing this one
            row = __shfl(rowv, t + 1);
            base = (size_t)row * DI + d;
            dl = dlt[base]; uv = u[base];
            xb = (const float4*)(xdbl + (size_t)row * XDP);
            B0 = xb[3]; B1 = xb[4]; B2 = xb[5]; B3 = xb[6];
            C0 = xb[7]; C1 = xb[8]; C2 = xb[9]; C3 = xb[10];
        }
        float y0 = 0.f, y1 = 0.f;
#pragma unroll
        for (int s = 0; s < 16; s++) {
            float dA = exp2f(dlc * A2[s]);
            h[s] = dA * h[s] + dv * Bc[s];
            if (s & 1) y1 += h[s] * Cv[s]; else y0 += h[s] * Cv[s];
        }
        y[(size_t)trow * DI + d] = y0 + y1 + uvc * dpv;
    }
}

extern "C" void kernel_launch(void* const* d_in, const int* in_sizes, int n_in,
                              void* d_out, int out_size, void* d_ws, size_t ws_size,
                              hipStream_t stream)
{
    const int* perm = (const int*)d_in[1];

    int* flag = (int*)d_ws;
    float* ws = (float*)d_ws + 16;
    size_t o = 0;

    Segs sg;
    int cum = 0;
    for (int i = 0; i < 19; i++) {
        sg.src[i] = d_in[3 + i];
        sg.off[i] = cum;
        cum += in_sizes[3 + i];
    }
    sg.off[19] = cum;                      // 550,848 elems
    float* wts = ws + o; o += (size_t)cum;
    bf16* wtsb = (bf16*)(ws + o); o += (size_t)(cum / 2);

    const float* conv_w  = wts + sg.off[3];
    const float* conv_b  = wts + sg.off[4];
    const float* dt_projw = wts + sg.off[6];
    const float* dt_projb = wts + sg.off[7];
    const float* A_log   = wts + sg.off[8];
    const float* Dpw     = wts + sg.off[9];
    const float* ln1_g   = wts + sg.off[0];
    const float* ln1_b   = wts + sg.off[1];
    const float* onorm_g = wts + sg.off[10];
    const float* onorm_b = wts + sg.off[11];
    const float* ln2_g   = wts + sg.off[13];
    const float* ln2_b   = wts + sg.off[14];
    const float* fc1_b   = wts + sg.off[16];
    const float* fc2_b   = wts + sg.off[18];
    const unsigned short* in_projw_b  = (const unsigned short*)(wtsb + sg.off[2]);
    const unsigned short* x_projw_b   = (const unsigned short*)(wtsb + sg.off[5]);
    const unsigned short* out_projw_b = (const unsigned short*)(wtsb + sg.off[12]);
    const unsigned short* fc1w_b      = (const unsigned short*)(wtsb + sg.off[15]);
    const unsigned short* fc2w_b      = (const unsigned short*)(wtsb + sg.off[17]);

    float* xw   = ws + o; o += (size_t)Mm * Cc;
    bf16*  hxb  = (bf16*)(ws + o); o += (size_t)Mm * Cc / 2;   // later: h2b
    float* xz   = ws + o; o += (size_t)Mm * 768;               // first half later: mbuf (bf16)
    float* u    = ws + o; o += (size_t)Mm * DI;
    bf16*  ub   = (bf16*)(ws + o); o += (size_t)Mm * DI / 2;   // later: ynb
    float* xdbl = ws + o; o += (size_t)Mm * XDP;
    float* dlt  = ws + o; o += (size_t)Mm * DI;
    float* y    = ws + o; o += (size_t)Mm * DI;                // later: x2
    float* Hend = ws + o; o += (size_t)Bb * NCH * DI * Ss;
    float* Pend = ws + o; o += (size_t)Bb * NCH * DI * Ss;
    // total ~27.6M floats ~ 110.3 MB (<= proven 111 MB)

    // 0. dtype detect + widen (fp32 + bf16 copies)
    detect_kernel<<<1, 64, 0, stream>>>((const unsigned int*)d_in[3], flag);
    convert_w<<<(cum + 255) / 256, 256, 0, stream>>>(sg, wts, wtsb, flag);
    convert_x<<<(Mm * Cc + 255) / 256, 256, 0, stream>>>(d_in[0], xw, Mm * Cc, flag);

    // 1. LN1 -> hxb (bf16)
    ln_kernel<Cc, false><<<Mm / 4, 256, 0, stream>>>(xw, ln1_g, ln1_b, nullptr, 0, 0, hxb);
    // 2. in_proj: xz = hxb @ W^T  [8192,768] fp32
    mfma_gemm<192, 192, 64, 0><<<dim3(Mm / 64, 12), 256, 0, stream>>>(
        (const unsigned short*)hxb, in_projw_b, 768, Cc, Cc, 768,
        nullptr, nullptr, 0, xz, nullptr, nullptr);
    // 3. depthwise conv + SiLU -> u fp32 + ub bf16
    conv_silu_kernel<<<Mm, DI, 0, stream>>>(xz, conv_w, conv_b, u, ub);
    // 4. x_proj: xdbl = ub @ W^T  [8192,44] (stride 48)
    mfma_gemm<384, 192, 32, 0><<<dim3(Mm / 32, 1), 256, 0, stream>>>(
        (const unsigned short*)ub, x_projw_b, 44, DI, DI, XDP,
        nullptr, nullptr, 0, xdbl, nullptr, nullptr);
    // 5. delta = softplus(dt @ dt_proj^T + b)
    delta_kernel<<<Mm * DI / 256, 256, 0, stream>>>(xdbl, dt_projw, dt_projb, dlt);
    // 6-8. chunked selective scan (zigzag order via perm gather)
    scanA_kernel<<<Bb * NCH * 6 / 4, 256, 0, stream>>>(dlt, u, xdbl, perm, A_log, Hend, Pend);
    scan_combine_kernel<<<Bb * DI * Ss / 256, 256, 0, stream>>>(Hend, Pend);
    scanC_kernel<<<Bb * NCH * 6 / 4, 256, 0, stream>>>(dlt, u, xdbl, perm, A_log, Dpw, Hend, y);
    // 9. out_norm(y) * silu(z) -> ynb (bf16, reuse ub)
    bf16* ynb = ub;
    ln_kernel<DI, true><<<Mm / 4, 256, 0, stream>>>(y, onorm_g, onorm_b, xz, 768, DI, ynb);
    // 10. out_proj + residual xw -> x2 fp32 (reuse y)
    float* x2 = y;
    mfma_gemm<384, 192, 64, 1><<<dim3(Mm / 64, 3), 256, 0, stream>>>(
        (const unsigned short*)ynb, out_projw_b, 192, DI, DI, Cc,
        nullptr, xw, Cc, x2, nullptr, nullptr);
    // 11. LN2: x2 -> h2b (bf16, reuse hxb)
    bf16* h2b = hxb;
    ln_kernel<Cc, false><<<Mm / 4, 256, 0, stream>>>(x2, ln2_g, ln2_b, nullptr, 0, 0, h2b);
    // 12. fc1 + bias + gelu -> mbuf bf16 (reuse xz region)
    bf16* mbuf = (bf16*)xz;
    mfma_gemm<192, 192, 64, 2><<<dim3(Mm / 64, 12), 256, 0, stream>>>(
        (const unsigned short*)h2b, fc1w_b, 768, Cc, Cc, HID,
        fc1_b, nullptr, 0, nullptr, mbuf, nullptr);
    // 13. fc2 + bias + residual x2 -> out (detected dtype)
    mfma_gemm<768, 192, 64, 3><<<dim3(Mm / 64, 3), 256, 0, stream>>>(
        (const unsigned short*)mbuf, fc2w_b, 192, HID, HID, Cc,
        fc2_b, x2, Cc, nullptr, d_out, flag);
}

// Round 6
// 298.527 us; speedup vs baseline: 1.0600x; 1.0600x over previous
//
#include <hip/hip_runtime.h>
#include <hip/hip_bf16.h>

// VSSBlock (VMamba SS2D) forward for B=8,H=32,W=32,C=192 on gfx950.
// Round 6: multi-strip register-B MFMA GEMMs (A-fragment reuse xS, higher TLP
// for narrow N), bf16 xz intermediate, convert_x eliminated.

typedef __hip_bfloat16 bf16;
#define DEV __device__ __forceinline__

typedef __attribute__((ext_vector_type(8))) short short8;
typedef __attribute__((ext_vector_type(4))) float floatx4;

constexpr int Bb   = 8;
constexpr int Hh   = 32;
constexpr int Ww   = 32;
constexpr int Cc   = 192;
constexpr int DI   = 384;
constexpr int Ss   = 16;
constexpr int Rr   = 12;
constexpr int HID  = 768;
constexpr int Mm   = 8192;   // B*H*W
constexpr int XDP  = 48;     // padded x_dbl row stride (44 -> 48)
constexpr int NCH  = 64;     // scan chunks
constexpr int CLEN = 16;     // steps per chunk (NCH*CLEN == 1024)

DEV float sigmoid_f(float x) { return 1.0f / (1.0f + __expf(-x)); }
DEV float silu_f(float x) { return x * sigmoid_f(x); }
DEV float gelu_f(float x) {
    float x3 = x * x * x;
    float t  = tanhf(0.7978845608028654f * (x + 0.044715f * x3));
    return 0.5f * x * (1.0f + t);
}

DEV void st16(float* __restrict__ p, const float* v) {
    float4* q = (float4*)p;
    q[0] = make_float4(v[0],v[1],v[2],v[3]);
    q[1] = make_float4(v[4],v[5],v[6],v[7]);
    q[2] = make_float4(v[8],v[9],v[10],v[11]);
    q[3] = make_float4(v[12],v[13],v[14],v[15]);
}
DEV void ld16(const float* __restrict__ p, float* v) {
    const float4* q = (const float4*)p;
    float4 a = q[0], b = q[1], c = q[2], d = q[3];
    v[0]=a.x; v[1]=a.y; v[2]=a.z; v[3]=a.w;
    v[4]=b.x; v[5]=b.y; v[6]=b.z; v[7]=b.w;
    v[8]=c.x; v[9]=c.y; v[10]=c.z; v[11]=c.w;
    v[12]=d.x; v[13]=d.y; v[14]=d.z; v[15]=d.w;
}

// ---------------- dtype detect: ln1_g is ones(192) ----------------
__global__ void detect_kernel(const unsigned int* __restrict__ g, int* __restrict__ flag) {
    if (threadIdx.x == 0 && blockIdx.x == 0)
        flag[0] = (g[0] == 0x3F800000u) ? 1 : 0;
}

// ---------------- widen all weight tensors: fp32 + bf16 copies ----------------
struct Segs {
    const void* src[19];
    int off[20];
};
__global__ __launch_bounds__(256) void convert_w(Segs sg, float* __restrict__ dst,
                                                 bf16* __restrict__ dstb,
                                                 const int* __restrict__ flag) {
    int i = blockIdx.x * 256 + threadIdx.x;
    if (i >= sg.off[19]) return;
    int f = flag[0];
    int s = 0;
    while (i >= sg.off[s + 1]) s++;
    int j = i - sg.off[s];
    float v = f ? ((const float*)sg.src[s])[j] : (float)((const bf16*)sg.src[s])[j];
    dst[i] = v;
    dstb[i] = __float2bfloat16(v);
}

// ---------------- LayerNorm (one wave per row), bf16 output ----------------
// SRC: 0 = fp32 input; 1 = input dtype per runtime flag (fp32/bf16).
template <int NC, int SRC, bool MULSILU>
__global__ __launch_bounds__(256) void ln_kernel(
    const void* __restrict__ x, const int* __restrict__ flagp,
    const float* __restrict__ g, const float* __restrict__ b,
    const bf16* __restrict__ zbuf, int zld, int zoff, bf16* __restrict__ out)
{
    constexpr int NPT = NC / 64;
    int wave = threadIdx.x >> 6, lane = threadIdx.x & 63;
    int row = blockIdx.x * 4 + wave;
    int f = (SRC == 1) ? flagp[0] : 1;
    float v[NPT];
    float s = 0.f;
#pragma unroll
    for (int j = 0; j < NPT; j++) {
        size_t idx = (size_t)row * NC + lane + 64 * j;
        v[j] = (SRC == 1 && !f) ? (float)((const bf16*)x)[idx] : ((const float*)x)[idx];
        s += v[j];
    }
#pragma unroll
    for (int m = 1; m < 64; m <<= 1) s += __shfl_xor(s, m);
    float mu = s * (1.0f / NC);
    float s2 = 0.f;
#pragma unroll
    for (int j = 0; j < NPT; j++) { float d = v[j] - mu; s2 += d * d; }
#pragma unroll
    for (int m = 1; m < 64; m <<= 1) s2 += __shfl_xor(s2, m);
    float rs = rsqrtf(s2 * (1.0f / NC) + 1e-5f);
    bf16* orow = out + (size_t)row * NC;
#pragma unroll
    for (int j = 0; j < NPT; j++) {
        int c = lane + 64 * j;
        float val = (v[j] - mu) * rs * g[c] + b[c];
        if (MULSILU) {
            float z = (float)zbuf[(size_t)row * zld + zoff + c];
            val *= silu_f(z);
        }
        orow[c] = __float2bfloat16(val);
    }
}

// ---------------- multi-strip MFMA GEMM: C[M,N] = A[M,K](bf16)*B[N,K]^T ----------------
// Each wave holds S 16-col B-strips (KCH-deep) in registers; A fragments are
// streamed from global and reused across the S strips. No LDS, no barriers.
// WM=4: waves take different m-tiles (same cols). WM=1: waves take different
// col-groups (same rows).
// EPI: 0 fp32 out; 1 +residual(flag dtype) fp32 out; 2 gelu(acc+bias) bf16 out;
//      3 acc+bias+fp32 residual -> flag dtype out; 4 plain bf16 out.
template <int Kt, int KCH, int MT, int S, int WM, int EPI>
__global__ __launch_bounds__(256) void mfma_gemm(
    const unsigned short* __restrict__ A, const unsigned short* __restrict__ Bw,
    int N, int lda, int ldb, int ldc,
    const float* __restrict__ bias, const void* __restrict__ res, int ldres,
    float* __restrict__ Cf, void* __restrict__ Co, const int* __restrict__ flagp)
{
    constexpr int NK = KCH / 32;
    int tid = threadIdx.x;
    int wid = tid >> 6, lane = tid & 63;
    int quad = lane >> 4, l16 = lane & 15;
    int mi = (WM == 4) ? wid : 0;
    int ni = (WM == 4) ? 0 : wid;
    int m0 = blockIdx.x * ((WM == 4 ? 4 : 1) * MT * 16) + mi * MT * 16;
    int n0 = blockIdx.y * ((WM == 1 ? 4 : 1) * S * 16) + ni * S * 16;

    int brow[S];
#pragma unroll
    for (int s = 0; s < S; s++) {
        int r = n0 + s * 16 + l16;
        brow[s] = (r < N) ? r : N - 1;   // clamp; guarded at store
    }

    floatx4 acc[MT][S];
#pragma unroll
    for (int i = 0; i < MT; i++)
#pragma unroll
        for (int s = 0; s < S; s++) acc[i][s] = (floatx4){0.f, 0.f, 0.f, 0.f};

    for (int kc = 0; kc < Kt; kc += KCH) {
        short8 bfr[S][NK];
#pragma unroll
        for (int s = 0; s < S; s++)
#pragma unroll
            for (int ks = 0; ks < NK; ks++)
                bfr[s][ks] = *(const short8*)(Bw + (size_t)brow[s] * ldb
                                              + kc + ks * 32 + quad * 8);
#pragma unroll
        for (int mt = 0; mt < MT; mt++) {
#pragma unroll
            for (int ks = 0; ks < NK; ks++) {
                short8 af = *(const short8*)(A + (size_t)(m0 + mt * 16 + l16) * lda
                                             + kc + ks * 32 + quad * 8);
#pragma unroll
                for (int s = 0; s < S; s++)
                    acc[mt][s] = __builtin_amdgcn_mfma_f32_16x16x32_bf16(
                        af, bfr[s][ks], acc[mt][s], 0, 0, 0);
            }
        }
    }

    int f = (EPI == 1 || EPI == 3) ? flagp[0] : 0;
#pragma unroll
    for (int mt = 0; mt < MT; mt++) {
#pragma unroll
        for (int s = 0; s < S; s++) {
            int n = n0 + s * 16 + l16;
            if (n >= N) continue;
            float bv = (EPI == 2 || EPI == 3) ? bias[n] : 0.f;
#pragma unroll
            for (int r = 0; r < 4; r++) {
                int m = m0 + mt * 16 + quad * 4 + r;
                float v = acc[mt][s][r];
                if (EPI == 1) {
                    float rv = f ? ((const float*)res)[(size_t)m * ldres + n]
                                 : (float)((const bf16*)res)[(size_t)m * ldres + n];
                    Cf[(size_t)m * ldc + n] = v + rv;
                } else if (EPI == 2) {
                    ((bf16*)Co)[(size_t)m * ldc + n] = __float2bfloat16(gelu_f(v + bv));
                } else if (EPI == 3) {
                    v += bv + ((const float*)res)[(size_t)m * ldres + n];
                    if (f) ((float*)Co)[(size_t)m * ldc + n] = v;
                    else   ((bf16*)Co)[(size_t)m * ldc + n] = __float2bfloat16(v);
                } else if (EPI == 4) {
                    ((bf16*)Co)[(size_t)m * ldc + n] = __float2bfloat16(v);
                } else {
                    Cf[(size_t)m * ldc + n] = v;
                }
            }
        }
    }
}

// ---------------- depthwise 3x3 conv + bias + SiLU (bf16 in, fp32+bf16 out) ----------------
__global__ __launch_bounds__(384) void conv_silu_kernel(
    const bf16* __restrict__ xz, const float* __restrict__ cw,
    const float* __restrict__ cb, float* __restrict__ u, bf16* __restrict__ ub)
{
    int d = threadIdx.x;
    int blk = blockIdx.x;              // b*1024 + l
    int l = blk & 1023, b = blk >> 10;
    int h = l >> 5, w = l & 31;
    float wv[9];
#pragma unroll
    for (int t = 0; t < 9; t++) wv[t] = cw[d * 9 + t];
    float acc = cb[d];
#pragma unroll
    for (int ki = 0; ki < 3; ki++) {
        int hh = h + ki - 1;
        if (hh < 0 || hh >= Hh) continue;
#pragma unroll
        for (int kj = 0; kj < 3; kj++) {
            int ww = w + kj - 1;
            if (ww < 0 || ww >= Ww) continue;
            acc += (float)xz[((size_t)(b << 10) + (hh << 5) + ww) * 768 + d] * wv[ki * 3 + kj];
        }
    }
    float s = silu_f(acc);
    u[(size_t)blk * DI + d] = s;
    ub[(size_t)blk * DI + d] = __float2bfloat16(s);
}

// ---------------- dt_proj + softplus -> delta ----------------
__global__ __launch_bounds__(256) void delta_kernel(
    const float* __restrict__ xdbl, const float* __restrict__ dtw,
    const float* __restrict__ dtb, float* __restrict__ dlt)
{
    int idx = blockIdx.x * 256 + threadIdx.x;   // m*384 + d
    int d = idx % DI, m = idx / DI;
    float acc = dtb[d];
    const float* xr = xdbl + (size_t)m * XDP;
#pragma unroll
    for (int r = 0; r < Rr; r++) acc += xr[r] * dtw[d * Rr + r];
    dlt[idx] = (acc > 20.f) ? acc : log1pf(__expf(acc));
}

// ---------------- scan pass A: per-chunk (prod dA, h_end), pipelined ----------------
__global__ __launch_bounds__(256) void scanA_kernel(
    const float* __restrict__ dlt, const float* __restrict__ u,
    const float* __restrict__ xdbl, const int* __restrict__ perm,
    const float* __restrict__ A_log,
    float* __restrict__ Hend, float* __restrict__ Pend)
{
    int wg = blockIdx.x * 4 + (threadIdx.x >> 6);
    int lane = threadIdx.x & 63;
    int dgrp = wg % 6; int rest = wg / 6;
    int chunk = rest % NCH; int b = rest / NCH;
    int d = dgrp * 64 + lane;

    int rowv = 0;
    if (lane < CLEN) rowv = (b << 10) + perm[chunk * CLEN + lane];

    float A2[16], h[16], P[16];
#pragma unroll
    for (int s = 0; s < 16; s++) {
        A2[s] = -__expf(A_log[d * 16 + s]) * 1.4426950408889634f;
        h[s] = 0.f; P[s] = 1.f;
    }

    int row = __shfl(rowv, 0);
    size_t base = (size_t)row * DI + d;
    float dl = dlt[base], uv = u[base];
    const float4* xb = (const float4*)(xdbl + (size_t)row * XDP);
    float4 B0 = xb[3], B1 = xb[4], B2 = xb[5], B3 = xb[6];

#pragma unroll 1
    for (int t = 0; t < CLEN; t++) {
        float dlc = dl;
        float dv  = dl * uv;
        float Bc[16] = {B0.x,B0.y,B0.z,B0.w, B1.x,B1.y,B1.z,B1.w,
                        B2.x,B2.y,B2.z,B2.w, B3.x,B3.y,B3.z,B3.w};
        if (t + 1 < CLEN) {   // prefetch next step while computing this one
            row = __shfl(rowv, t + 1);
            base = (size_t)row * DI + d;
            dl = dlt[base]; uv = u[base];
            xb = (const float4*)(xdbl + (size_t)row * XDP);
            B0 = xb[3]; B1 = xb[4]; B2 = xb[5]; B3 = xb[6];
        }
#pragma unroll
        for (int s = 0; s < 16; s++) {
            float dA = exp2f(dlc * A2[s]);
            h[s] = dA * h[s] + dv * Bc[s];
            P[s] *= dA;
        }
    }
    size_t o = ((size_t)((b * NCH + chunk) * DI + d)) * 16;
    st16(Hend + o, h);
    st16(Pend + o, P);
}

// ---------------- scan combine: in-place exclusive prefix over Hend ----------------
__global__ __launch_bounds__(256) void scan_combine_kernel(
    float* __restrict__ Hend, const float* __restrict__ Pend)
{
    int idx = blockIdx.x * 256 + threadIdx.x;   // b*(384*16) + d*16 + s
    int s = idx & 15; int dd = (idx >> 4) % DI; int b = (idx >> 4) / DI;
    float hv = 0.f;
    for (int c = 0; c < NCH; c++) {
        size_t o = ((size_t)((b * NCH + c) * DI + dd)) * 16 + s;
        float he = Hend[o], pe = Pend[o];
        Hend[o] = hv;                 // exclusive prefix (h_in for chunk c)
        hv = he + pe * hv;
    }
}

// ---------------- scan pass C: recompute with true h_in, emit y; pipelined ----------------
__global__ __launch_bounds__(256) void scanC_kernel(
    const float* __restrict__ dlt, const float* __restrict__ u,
    const float* __restrict__ xdbl, const int* __restrict__ perm,
    const float* __restrict__ A_log, const float* __restrict__ Dp,
    const float* __restrict__ Hin, float* __restrict__ y)
{
    int wg = blockIdx.x * 4 + (threadIdx.x >> 6);
    int lane = threadIdx.x & 63;
    int dgrp = wg % 6; int rest = wg / 6;
    int chunk = rest % NCH; int b = rest / NCH;
    int d = dgrp * 64 + lane;

    int rowv = 0;
    if (lane < CLEN) rowv = (b << 10) + perm[chunk * CLEN + lane];

    float A2[16], h[16];
#pragma unroll
    for (int s = 0; s < 16; s++)
        A2[s] = -__expf(A_log[d * 16 + s]) * 1.4426950408889634f;
    ld16(Hin + ((size_t)((b * NCH + chunk) * DI + d)) * 16, h);
    float dpv = Dp[d];

    int row = __shfl(rowv, 0);
    size_t base = (size_t)row * DI + d;
    float dl = dlt[base], uv = u[base];
    const float4* xb = (const float4*)(xdbl + (size_t)row * XDP);
    float4 B0 = xb[3], B1 = xb[4], B2 = xb[5], B3 = xb[6];
    float4 C0 = xb[7], C1 = xb[8], C2 = xb[9], C3 = xb[10];

#pragma unroll 1
    for (int t = 0; t < CLEN; t++) {
        int trow = row;
        float dlc = dl, uvc = uv;
        float dv  = dl * uv;
        float Bc[16] = {B0.x,B0.y,B0.z,B0.w, B1.x,B1.y,B1.z,B1.w,
                        B2.x,B2.y,B2.z,B2.w, B3.x,B3.y,B3.z,B3.w};
        float Cv[16] = {C0.x,C0.y,C0.z,C0.w, C1.x,C1.y,C1.z,C1.w,
                        C2.x,C2.y,C2.z,C2.w, C3.x,C3.y,C3.z,C3.w};
        if (t + 1 < CLEN) {   // prefetch next step while computing this one
            row = __shfl(rowv, t + 1);
            base = (size_t)row * DI + d;
            dl = dlt[base]; uv = u[base];
            xb = (const float4*)(xdbl + (size_t)row * XDP);
            B0 = xb[3]; B1 = xb[4]; B2 = xb[5]; B3 = xb[6];
            C0 = xb[7]; C1 = xb[8]; C2 = xb[9]; C3 = xb[10];
        }
        float y0 = 0.f, y1 = 0.f;
#pragma unroll
        for (int s = 0; s < 16; s++) {
            float dA = exp2f(dlc * A2[s]);
            h[s] = dA * h[s] + dv * Bc[s];
            if (s & 1) y1 += h[s] * Cv[s]; else y0 += h[s] * Cv[s];
        }
        y[(size_t)trow * DI + d] = y0 + y1 + uvc * dpv;
    }
}

extern "C" void kernel_launch(void* const* d_in, const int* in_sizes, int n_in,
                              void* d_out, int out_size, void* d_ws, size_t ws_size,
                              hipStream_t stream)
{
    const int* perm = (const int*)d_in[1];

    int* flag = (int*)d_ws;
    float* ws = (float*)d_ws + 16;
    size_t o = 0;

    Segs sg;
    int cum = 0;
    for (int i = 0; i < 19; i++) {
        sg.src[i] = d_in[3 + i];
        sg.off[i] = cum;
        cum += in_sizes[3 + i];
    }
    sg.off[19] = cum;                      // 550,848 elems
    float* wts = ws + o; o += (size_t)cum;
    bf16* wtsb = (bf16*)(ws + o); o += (size_t)(cum / 2);

    const float* conv_w  = wts + sg.off[3];
    const float* conv_b  = wts + sg.off[4];
    const float* dt_projw = wts + sg.off[6];
    const float* dt_projb = wts + sg.off[7];
    const float* A_log   = wts + sg.off[8];
    const float* Dpw     = wts + sg.off[9];
    const float* ln1_g   = wts + sg.off[0];
    const float* ln1_b   = wts + sg.off[1];
    const float* onorm_g = wts + sg.off[10];
    const float* onorm_b = wts + sg.off[11];
    const float* ln2_g   = wts + sg.off[13];
    const float* ln2_b   = wts + sg.off[14];
    const float* fc1_b   = wts + sg.off[16];
    const float* fc2_b   = wts + sg.off[18];
    const unsigned short* in_projw_b  = (const unsigned short*)(wtsb + sg.off[2]);
    const unsigned short* x_projw_b   = (const unsigned short*)(wtsb + sg.off[5]);
    const unsigned short* out_projw_b = (const unsigned short*)(wtsb + sg.off[12]);
    const unsigned short* fc1w_b      = (const unsigned short*)(wtsb + sg.off[15]);
    const unsigned short* fc2w_b      = (const unsigned short*)(wtsb + sg.off[17]);

    bf16*  hxb  = (bf16*)(ws + o); o += (size_t)Mm * Cc / 2;   // later: h2b
    bf16*  xzb  = (bf16*)(ws + o); o += (size_t)Mm * 768 / 2;  // bf16 xm|z; later: mbuf
    float* u    = ws + o; o += (size_t)Mm * DI;
    bf16*  ub   = (bf16*)(ws + o); o += (size_t)Mm * DI / 2;   // later: ynb
    float* xdbl = ws + o; o += (size_t)Mm * XDP;
    float* dlt  = ws + o; o += (size_t)Mm * DI;
    float* y    = ws + o; o += (size_t)Mm * DI;                // later: x2
    float* Hend = ws + o; o += (size_t)Bb * NCH * DI * Ss;
    float* Pend = ws + o; o += (size_t)Bb * NCH * DI * Ss;
    // total ~21M floats ~ 84 MB

    // 0. dtype detect + weight widen (fp32 + bf16 copies)
    detect_kernel<<<1, 64, 0, stream>>>((const unsigned int*)d_in[3], flag);
    convert_w<<<(cum + 255) / 256, 256, 0, stream>>>(sg, wts, wtsb, flag);

    // 1. LN1 (reads d_in[0] in detected dtype) -> hxb bf16
    ln_kernel<Cc, 1, false><<<Mm / 4, 256, 0, stream>>>(
        d_in[0], flag, ln1_g, ln1_b, nullptr, 0, 0, hxb);
    // 2. in_proj: xzb = hxb @ W^T  [8192,768] bf16
    mfma_gemm<192, 192, 4, 2, 1, 4><<<dim3(Mm / 64, 6), 256, 0, stream>>>(
        (const unsigned short*)hxb, in_projw_b, 768, Cc, Cc, 768,
        nullptr, nullptr, 0, nullptr, xzb, nullptr);
    // 3. depthwise conv + SiLU -> u fp32 + ub bf16
    conv_silu_kernel<<<Mm, DI, 0, stream>>>(xzb, conv_w, conv_b, u, ub);
    // 4. x_proj: xdbl = ub @ W^T  [8192,44] fp32 (stride 48)
    mfma_gemm<384, 192, 1, 3, 4, 0><<<dim3(Mm / 64, 1), 256, 0, stream>>>(
        (const unsigned short*)ub, x_projw_b, 44, DI, DI, XDP,
        nullptr, nullptr, 0, xdbl, nullptr, nullptr);
    // 5. delta = softplus(dt @ dt_proj^T + b)
    delta_kernel<<<Mm * DI / 256, 256, 0, stream>>>(xdbl, dt_projw, dt_projb, dlt);
    // 6-8. chunked selective scan (zigzag order via perm gather)
    scanA_kernel<<<Bb * NCH * 6 / 4, 256, 0, stream>>>(dlt, u, xdbl, perm, A_log, Hend, Pend);
    scan_combine_kernel<<<Bb * DI * Ss / 256, 256, 0, stream>>>(Hend, Pend);
    scanC_kernel<<<Bb * NCH * 6 / 4, 256, 0, stream>>>(dlt, u, xdbl, perm, A_log, Dpw, Hend, y);
    // 9. out_norm(y) * silu(z from xzb cols 384..767) -> ynb (bf16, reuse ub)
    bf16* ynb = ub;
    ln_kernel<DI, 0, true><<<Mm / 4, 256, 0, stream>>>(
        y, nullptr, onorm_g, onorm_b, xzb, 768, DI, ynb);
    // 10. out_proj + residual d_in[0] -> x2 fp32 (reuse y)
    float* x2 = y;
    mfma_gemm<384, 192, 1, 3, 1, 1><<<dim3(Mm / 16, 1), 256, 0, stream>>>(
        (const unsigned short*)ynb, out_projw_b, Cc, DI, DI, Cc,
        nullptr, d_in[0], Cc, x2, nullptr, flag);
    // 11. LN2: x2 -> h2b (bf16, reuse hxb)
    bf16* h2b = hxb;
    ln_kernel<Cc, 0, false><<<Mm / 4, 256, 0, stream>>>(
        x2, nullptr, ln2_g, ln2_b, nullptr, 0, 0, h2b);
    // 12. fc1 + bias + gelu -> mbuf bf16 (reuse xzb)
    bf16* mbuf = xzb;
    mfma_gemm<192, 192, 4, 2, 1, 2><<<dim3(Mm / 64, 6), 256, 0, stream>>>(
        (const unsigned short*)h2b, fc1w_b, 768, Cc, Cc, HID,
        fc1_b, nullptr, 0, nullptr, mbuf, nullptr);
    // 13. fc2 + bias + residual x2 -> out (detected dtype)
    mfma_gemm<768, 192, 1, 3, 1, 3><<<dim3(Mm / 16, 1), 256, 0, stream>>>(
        (const unsigned short*)mbuf, fc2w_b, Cc, HID, HID, Cc,
        fc2_b, x2, Cc, nullptr, d_out, flag);
}